// Round 2
// baseline (12613.897 us; speedup 1.0000x reference)
//
#include <hip/hip_runtime.h>
#include <hip/hip_bf16.h>

#define TT 1000
#define HH 512
#define HH2 1024
#define DT_ 0.01f
// sqrt(2*DT*SIGMA_RECUR^2), sqrt(2*DT*SIGMA_INPUT^2)
#define PH_SCALE 7.0710678118654745e-4f
#define PI_SCALE 7.0710678118654745e-3f

typedef short s16x8 __attribute__((ext_vector_type(8)));
typedef float f32x4 __attribute__((ext_vector_type(4)));

// Persistent RNN kernel.
// Grid: 64 blocks x 256 threads (4 waves). Wave = output tile (mt, nt):
//   mt = blockIdx>>4 (batch tile, 16 rows), nt = (blockIdx&15)*4 + waveid (16 cols).
// 4 independent barrier groups (one per mt); group = 16 blocks. The recurrence
// is independent per batch row, so groups never sync with each other.
// W_rec (16 cols x 1024 K per wave) is held in 128 VGPRs/lane for all steps.
// x-state, inhib, input weights are register-resident.
__global__ __launch_bounds__(256, 1) void rnn_persistent(
    const float* __restrict__ inp, const float* __restrict__ hn,
    const float* __restrict__ x0g, const float* __restrict__ inhib,
    const float* __restrict__ ph, const float* __restrict__ pig,
    const float* __restrict__ s2s, const float* __restrict__ a2a,
    const float* __restrict__ a2s, const float* __restrict__ s2a,
    const float* __restrict__ iw,
    float* __restrict__ rnn_out, float* __restrict__ x_out,
    __hip_bfloat16* __restrict__ hbuf,   // [2][64][1024] bf16
    unsigned* __restrict__ bar)          // [4] counters, 256B stride
{
    const int tid  = threadIdx.x;
    const int wid  = tid >> 6;
    const int lane = tid & 63;
    const int mt   = blockIdx.x >> 4;      // batch tile / barrier group
    const int nb   = blockIdx.x & 15;
    const int nt   = nb * 4 + wid;         // column tile
    const int l15  = lane & 15;
    const int lq   = lane >> 4;
    const int i    = nt * 16 + l15;        // output column (= W row)
    unsigned* bcnt = bar + mt * 64;

    // ---- W fragments in registers (one-time, f32 -> bf16) ----
    // frag kc: lane reads W[i][kc*32 + lq*8 .. +8]
    s16x8 w[32];
    #pragma unroll
    for (int kc = 0; kc < 32; ++kc) {
        const int j = kc * 32 + lq * 8;
        const float* src;
        if (i < HH) src = (j < HH) ? (s2s + (size_t)i * HH + j)
                                   : (a2s + (size_t)i * HH + (j - HH));
        else        src = (j < HH) ? (s2a + (size_t)(i - HH) * HH + j)
                                   : (a2a + (size_t)(i - HH) * HH + (j - HH));
        const float4 f0 = *(const float4*)(src);
        const float4 f1 = *(const float4*)(src + 4);
        union { s16x8 v; __hip_bfloat16 h[8]; } u;
        u.h[0] = __float2bfloat16(f0.x); u.h[1] = __float2bfloat16(f0.y);
        u.h[2] = __float2bfloat16(f0.z); u.h[3] = __float2bfloat16(f0.w);
        u.h[4] = __float2bfloat16(f1.x); u.h[5] = __float2bfloat16(f1.y);
        u.h[6] = __float2bfloat16(f1.z); u.h[7] = __float2bfloat16(f1.w);
        w[kc] = u.v;
    }

    // ---- register-resident epilogue state ----
    const bool isStr = (i < HH);
    float iw0 = 0.f, iw1 = 0.f, iw2 = 0.f, iw3 = 0.f;
    if (isStr) {
        iw0 = iw[i]; iw1 = iw[HH2 + i]; iw2 = iw[2 * HH2 + i]; iw3 = iw[3 * HH2 + i];
    }
    float xr[4], inh[4];
    #pragma unroll
    for (int r = 0; r < 4; ++r) {
        const int b = mt * 16 + lq * 4 + r;
        xr[r]  = x0g[(size_t)b * HH2 + i];
        inh[r] = inhib[(size_t)b * HH2 + i];
    }

    // ---- init h buffer 0 (this wave's 16x16 tile) ----
    #pragma unroll
    for (int r = 0; r < 4; ++r) {
        const int b = mt * 16 + lq * 4 + r;
        hbuf[(size_t)b * HH2 + i] = __float2bfloat16(hn[(size_t)b * HH2 + i]);
    }

    // prefetch t=0 inputs (read-only, never stale)
    float4 ipf[4];
    #pragma unroll
    for (int r = 0; r < 4; ++r) {
        const int b = mt * 16 + lq * 4 + r;
        ipf[r] = *(const float4*)(inp + ((size_t)b * TT + 0) * 4);
    }
    float phv = ph[0], piv = pig[0];

    // barrier #1: h0 visible to group
    __builtin_amdgcn_fence(__ATOMIC_RELEASE, "agent");
    __syncthreads();
    if (tid == 0) {
        __hip_atomic_fetch_add(bcnt, 1u, __ATOMIC_RELAXED, __HIP_MEMORY_SCOPE_AGENT);
        while (__hip_atomic_load(bcnt, __ATOMIC_RELAXED, __HIP_MEMORY_SCOPE_AGENT) < 16u) {}
    }
    __syncthreads();
    __builtin_amdgcn_fence(__ATOMIC_ACQUIRE, "agent");

    const __hip_bfloat16* hb0 = hbuf;
    const __hip_bfloat16* hb1 = hbuf + 65536;

    #pragma unroll 1
    for (int t = 0; t < TT; ++t) {
        const __hip_bfloat16* hp  = (t & 1) ? hb1 : hb0;
        __hip_bfloat16*       hnx = (__hip_bfloat16*)((t & 1) ? hb0 : hb1);
        const __hip_bfloat16* ap  = hp + (size_t)(mt * 16 + l15) * HH2 + lq * 8;

        f32x4 acc0 = {0.f, 0.f, 0.f, 0.f};
        f32x4 acc1 = {0.f, 0.f, 0.f, 0.f};
        #pragma unroll
        for (int kc = 0; kc < 32; kc += 2) {
            s16x8 a0 = *(const s16x8*)(ap + kc * 32);
            s16x8 a1 = *(const s16x8*)(ap + kc * 32 + 32);
            acc0 = __builtin_amdgcn_mfma_f32_16x16x32_bf16(a0, w[kc],     acc0, 0, 0, 0);
            acc1 = __builtin_amdgcn_mfma_f32_16x16x32_bf16(a1, w[kc + 1], acc1, 0, 0, 0);
        }

        const float phs = PH_SCALE * phv;
        const float pis = PI_SCALE * piv;
        float xn_[4], hv_[4];
        #pragma unroll
        for (int r = 0; r < 4; ++r) {
            const int b = mt * 16 + lq * 4 + r;
            float drive = 0.f;
            if (isStr) drive = (ipf[r].x + pis) * iw0 + (ipf[r].y + pis) * iw1 +
                               (ipf[r].z + pis) * iw2 + (ipf[r].w + pis) * iw3;
            const float xp = xr[r];
            const float xn = xp + DT_ * (-xp + (acc0[r] + acc1[r]) + drive + inh[r]) + phs;
            const float hv = fmaxf(xn, 0.f);
            xr[r] = xn; xn_[r] = xn; hv_[r] = hv;
            hnx[(size_t)b * HH2 + i] = __float2bfloat16(hv);
        }

        // publish h_next, arrive
        __builtin_amdgcn_fence(__ATOMIC_RELEASE, "agent");
        __syncthreads();
        if (tid == 0)
            __hip_atomic_fetch_add(bcnt, 1u, __ATOMIC_RELAXED, __HIP_MEMORY_SCOPE_AGENT);

        // off-critical-path: history stores + next-step input prefetch
        #pragma unroll
        for (int r = 0; r < 4; ++r) {
            const int b = mt * 16 + lq * 4 + r;
            const size_t o = ((size_t)b * TT + t) * HH2 + i;
            __builtin_nontemporal_store(hv_[r], rnn_out + o);
            __builtin_nontemporal_store(xn_[r], x_out + o);
        }
        const int tn = (t + 1 < TT) ? (t + 1) : t;
        #pragma unroll
        for (int r = 0; r < 4; ++r) {
            const int b = mt * 16 + lq * 4 + r;
            ipf[r] = *(const float4*)(inp + ((size_t)b * TT + tn) * 4);
        }
        phv = ph[tn]; piv = pig[tn];

        // wait for group, acquire
        const unsigned tgt = 16u * (unsigned)(t + 2);
        if (tid == 0)
            while (__hip_atomic_load(bcnt, __ATOMIC_RELAXED, __HIP_MEMORY_SCOPE_AGENT) < tgt) {}
        __syncthreads();
        __builtin_amdgcn_fence(__ATOMIC_ACQUIRE, "agent");
    }
}

// ---------------- fc1: out[b,t] = dot(rnn_out[b,t,512:1024], fc1_w[512:1024]) + fc1_b ----------------
__global__ __launch_bounds__(256) void fc1_kernel(
    const float* __restrict__ rnn_out, const float* __restrict__ fc1_w,
    const float* __restrict__ fc1_b, float* __restrict__ out)
{
    const int wid = blockIdx.x * 4 + (threadIdx.x >> 6);  // [0, 64000)
    const int lane = threadIdx.x & 63;
    const float* p = rnn_out + (size_t)wid * HH2 + HH + lane * 8;
    const float* w = fc1_w + HH + lane * 8;
    f32x4 v0 = *(const f32x4*)(p);
    f32x4 v1 = *(const f32x4*)(p + 4);
    f32x4 w0 = *(const f32x4*)(w);
    f32x4 w1 = *(const f32x4*)(w + 4);
    float s = v0[0]*w0[0] + v0[1]*w0[1] + v0[2]*w0[2] + v0[3]*w0[3]
            + v1[0]*w1[0] + v1[1]*w1[1] + v1[2]*w1[2] + v1[3]*w1[3];
    #pragma unroll
    for (int off = 32; off; off >>= 1) s += __shfl_xor(s, off);
    if (lane == 0) out[wid] = s + fc1_b[0];
}

// ---------------- last-state extraction ----------------
__global__ __launch_bounds__(256) void last_kernel(
    const float* __restrict__ rnn_out, const float* __restrict__ x_out,
    float* __restrict__ hn_last, float* __restrict__ x_last)
{
    const int idx = blockIdx.x * 256 + threadIdx.x;  // [0, 65536)
    const int b = idx >> 10;
    const int i = idx & 1023;
    const size_t o = ((size_t)b * TT + (TT - 1)) * HH2 + i;
    hn_last[idx] = rnn_out[o];
    x_last[idx]  = x_out[o];
}

extern "C" void kernel_launch(void* const* d_in, const int* in_sizes, int n_in,
                              void* d_out, int out_size, void* d_ws, size_t ws_size,
                              hipStream_t stream) {
    const float* inp   = (const float*)d_in[0];   // [64,1000,4]
    const float* hn    = (const float*)d_in[1];   // [1,64,1024]
    const float* x     = (const float*)d_in[2];   // [1,64,1024]
    const float* inhib = (const float*)d_in[3];   // [64,1024]
    const float* ph    = (const float*)d_in[4];   // [1000]
    const float* pi    = (const float*)d_in[5];   // [1000]
    const float* s2s   = (const float*)d_in[6];   // [512,512]
    const float* a2a   = (const float*)d_in[7];
    const float* a2s   = (const float*)d_in[8];
    const float* s2a   = (const float*)d_in[9];
    const float* iw    = (const float*)d_in[10];  // [4,1024]
    const float* fw    = (const float*)d_in[11];  // [1,1024]
    const float* fb    = (const float*)d_in[12];  // [1]

    // Output tuple layout (floats): out | hn_last | rnn_out | x_last | x_out
    float* out     = (float*)d_out;               // 64000
    float* hn_last = out + 64000;                 // 65536
    float* rnn_out = out + 129536;                // 65,536,000
    float* x_last  = out + 65665536;              // 65536
    float* x_out   = out + 65731072;              // 65,536,000

    // Workspace: bar (1 KB) | pad | hbuf [2][64][1024] bf16 (256 KB)
    unsigned* bar = (unsigned*)d_ws;
    __hip_bfloat16* hbuf = (__hip_bfloat16*)((char*)d_ws + 4096);

    hipMemsetAsync(bar, 0, 1024, stream);
    rnn_persistent<<<64, 256, 0, stream>>>(inp, hn, x, inhib, ph, pi,
                                           s2s, a2a, a2s, s2a, iw,
                                           rnn_out, x_out, hbuf, bar);
    fc1_kernel<<<16000, 256, 0, stream>>>(rnn_out, fw, fb, out);
    last_kernel<<<256, 256, 0, stream>>>(rnn_out, x_out, hn_last, x_last);
}

// Round 3
// 3509.240 us; speedup vs baseline: 3.5945x; 3.5945x over previous
//
#include <hip/hip_runtime.h>
#include <hip/hip_bf16.h>

#define TT 1000
#define HH 512
#define HH2 1024
#define DT_ 0.01f
// sqrt(2*DT*SIGMA_RECUR^2), sqrt(2*DT*SIGMA_INPUT^2)
#define PH_SCALE 7.0710678118654745e-4f
#define PI_SCALE 7.0710678118654745e-3f

typedef short s16x8 __attribute__((ext_vector_type(8)));
typedef float f32x4 __attribute__((ext_vector_type(4)));

static __device__ __forceinline__ unsigned short bf16_bits(float f) {
    union { __hip_bfloat16 h; unsigned short u; } b;
    b.h = __float2bfloat16(f);
    return b.u;
}

// Persistent RNN kernel. Grid: 64 blocks x 256 threads (4 waves).
// Wave = output tile (mt, nt): mt = blockIdx>>4 (16 batch rows), nt = (blockIdx&15)*4 + wid.
// 4 independent barrier groups of 16 blocks (one per mt).
// Coherence is hand-rolled: h exchanged via relaxed agent-scope atomics
// (device-coherent sc0/sc1 accesses, NO fences -> no buffer_wbl2 / buffer_inv per step).
// W_rec slice (16 cols x 1024) in 128 VGPRs/lane; x-state/inhib/iw register-resident.
// h tile staged once per block into XOR-swizzled LDS for conflict-free ds_read_b128.
__global__ __launch_bounds__(256, 1) void rnn_persistent(
    const float* __restrict__ inp, const float* __restrict__ hn,
    const float* __restrict__ x0g, const float* __restrict__ inhib,
    const float* __restrict__ ph, const float* __restrict__ pig,
    const float* __restrict__ s2s, const float* __restrict__ a2a,
    const float* __restrict__ a2s, const float* __restrict__ s2a,
    const float* __restrict__ iw,
    float* __restrict__ rnn_out, float* __restrict__ x_out,
    unsigned short* __restrict__ hbuf,   // [2][64][1024] bf16 bits
    unsigned* __restrict__ bar)          // [4] counters, 256 B apart
{
    const int tid  = threadIdx.x;
    const int wid  = tid >> 6;
    const int lane = tid & 63;
    const int mt   = blockIdx.x >> 4;      // batch tile / barrier group
    const int nb   = blockIdx.x & 15;
    const int nt   = nb * 4 + wid;         // column tile
    const int l15  = lane & 15;
    const int lq   = lane >> 4;
    const int i    = nt * 16 + l15;        // output column (= W row)
    unsigned* bcnt = bar + mt * 64;

    __shared__ __align__(16) unsigned short hlds[16 * 1024];  // 32 KB, swizzled

    // ---- W fragments in registers (one-time, f32 -> bf16) ----
    s16x8 w[32];
    #pragma unroll
    for (int kc = 0; kc < 32; ++kc) {
        const int j = kc * 32 + lq * 8;
        const float* src;
        if (i < HH) src = (j < HH) ? (s2s + (size_t)i * HH + j)
                                   : (a2s + (size_t)i * HH + (j - HH));
        else        src = (j < HH) ? (s2a + (size_t)(i - HH) * HH + j)
                                   : (a2a + (size_t)(i - HH) * HH + (j - HH));
        const float4 f0 = *(const float4*)(src);
        const float4 f1 = *(const float4*)(src + 4);
        union { s16x8 v; unsigned short us[8]; } u;
        u.us[0] = bf16_bits(f0.x); u.us[1] = bf16_bits(f0.y);
        u.us[2] = bf16_bits(f0.z); u.us[3] = bf16_bits(f0.w);
        u.us[4] = bf16_bits(f1.x); u.us[5] = bf16_bits(f1.y);
        u.us[6] = bf16_bits(f1.z); u.us[7] = bf16_bits(f1.w);
        w[kc] = u.v;
    }

    // ---- register-resident epilogue state ----
    const bool isStr = (i < HH);
    float iw0 = 0.f, iw1 = 0.f, iw2 = 0.f, iw3 = 0.f;
    if (isStr) {
        iw0 = iw[i]; iw1 = iw[HH2 + i]; iw2 = iw[2 * HH2 + i]; iw3 = iw[3 * HH2 + i];
    }
    float xr[4], inh[4];
    #pragma unroll
    for (int r = 0; r < 4; ++r) {
        const int b = mt * 16 + lq * 4 + r;
        xr[r]  = x0g[(size_t)b * HH2 + i];
        inh[r] = inhib[(size_t)b * HH2 + i];
    }

    // publish this wave's 16x16 tile (4 row-values per lane) as coherent u32 stores
    auto publishTile = [&](unsigned short* dst, const float v[4]) {
        float pv[4];
        #pragma unroll
        for (int r = 0; r < 4; ++r) pv[r] = __shfl_xor(v[r], 1);
        if ((l15 & 1) == 0) {
            #pragma unroll
            for (int r = 0; r < 4; ++r) {
                const int b = mt * 16 + lq * 4 + r;
                const unsigned val = (unsigned)bf16_bits(v[r]) |
                                     ((unsigned)bf16_bits(pv[r]) << 16);
                __hip_atomic_store((unsigned*)(dst + (size_t)b * HH2 + i), val,
                                   __ATOMIC_RELAXED, __HIP_MEMORY_SCOPE_AGENT);
            }
        }
    };

    // cooperative coherent load of h tile [16][1024] bf16 -> swizzled LDS
    auto stageTile = [&](const unsigned short* srcbuf) {
        const unsigned long long* base =
            (const unsigned long long*)(srcbuf + (size_t)mt * 16 * HH2);
        unsigned long long v0[8], v1[8];
        #pragma unroll
        for (int rd = 0; rd < 8; ++rd) {
            const int g   = tid + rd * 256;     // 16B-chunk id, [0,2048)
            const int row = g >> 7;
            const int c16 = g & 127;
            const unsigned long long* p = base + row * 256 + c16 * 2;
            v0[rd] = __hip_atomic_load(p,     __ATOMIC_RELAXED, __HIP_MEMORY_SCOPE_AGENT);
            v1[rd] = __hip_atomic_load(p + 1, __ATOMIC_RELAXED, __HIP_MEMORY_SCOPE_AGENT);
        }
        #pragma unroll
        for (int rd = 0; rd < 8; ++rd) {
            const int g    = tid + rd * 256;
            const int row  = g >> 7;
            const int c16  = g & 127;
            const int slot = c16 ^ (row & 7);   // XOR swizzle (16B granules)
            unsigned long long* lp = (unsigned long long*)&hlds[row * 1024 + slot * 8];
            lp[0] = v0[rd]; lp[1] = v1[rd];
        }
    };

    // ---- init: h0 -> buffer 0, then group barrier ----
    {
        float h0v[4];
        #pragma unroll
        for (int r = 0; r < 4; ++r) {
            const int b = mt * 16 + lq * 4 + r;
            h0v[r] = hn[(size_t)b * HH2 + i];
        }
        publishTile(hbuf, h0v);
    }
    // prefetch t=0 inputs
    float4 ipf[4];
    #pragma unroll
    for (int r = 0; r < 4; ++r) {
        const int b = mt * 16 + lq * 4 + r;
        ipf[r] = *(const float4*)(inp + ((size_t)b * TT + 0) * 4);
    }
    float phv = ph[0], piv = pig[0];

    asm volatile("s_waitcnt vmcnt(0)" ::: "memory");
    __syncthreads();
    if (tid == 0) {
        __hip_atomic_fetch_add(bcnt, 1u, __ATOMIC_RELAXED, __HIP_MEMORY_SCOPE_AGENT);
        while (__hip_atomic_load(bcnt, __ATOMIC_RELAXED, __HIP_MEMORY_SCOPE_AGENT) < 16u) {}
    }
    __syncthreads();

    const unsigned short* hb0 = hbuf;
    const unsigned short* hb1 = hbuf + 65536;

    #pragma unroll 1
    for (int t = 0; t < TT; ++t) {
        const unsigned short* hp  = (t & 1) ? hb1 : hb0;
        unsigned short*       hnx = (unsigned short*)((t & 1) ? hb0 : hb1);

        stageTile(hp);
        __syncthreads();

        f32x4 acc0 = {0.f, 0.f, 0.f, 0.f};
        f32x4 acc1 = {0.f, 0.f, 0.f, 0.f};
        const unsigned short* arow = hlds + l15 * 1024;
        #pragma unroll
        for (int kc = 0; kc < 32; kc += 2) {
            const int s0 = ((kc << 2) | lq) ^ (l15 & 7);
            const int s1 = (((kc + 1) << 2) | lq) ^ (l15 & 7);
            s16x8 a0 = *(const s16x8*)(arow + s0 * 8);
            s16x8 a1 = *(const s16x8*)(arow + s1 * 8);
            acc0 = __builtin_amdgcn_mfma_f32_16x16x32_bf16(a0, w[kc],     acc0, 0, 0, 0);
            acc1 = __builtin_amdgcn_mfma_f32_16x16x32_bf16(a1, w[kc + 1], acc1, 0, 0, 0);
        }

        const float phs = PH_SCALE * phv;
        const float pis = PI_SCALE * piv;
        float xn_[4], hv_[4];
        #pragma unroll
        for (int r = 0; r < 4; ++r) {
            float drive = 0.f;
            if (isStr) drive = (ipf[r].x + pis) * iw0 + (ipf[r].y + pis) * iw1 +
                               (ipf[r].z + pis) * iw2 + (ipf[r].w + pis) * iw3;
            const float xp = xr[r];
            const float xn = xp + DT_ * (-xp + (acc0[r] + acc1[r]) + drive + inh[r]) + phs;
            const float hv = fmaxf(xn, 0.f);
            xr[r] = xn; xn_[r] = xn; hv_[r] = hv;
        }

        // publish h[t+1], then arrive (h stores are coherent write-through; vmcnt(0)
        // guarantees they reached the coherence point before the counter bump)
        publishTile(hnx, hv_);
        asm volatile("s_waitcnt vmcnt(0)" ::: "memory");
        __syncthreads();
        if (tid == 0)
            __hip_atomic_fetch_add(bcnt, 1u, __ATOMIC_RELAXED, __HIP_MEMORY_SCOPE_AGENT);

        // off-critical-path: history stores + next-step input prefetch
        #pragma unroll
        for (int r = 0; r < 4; ++r) {
            const int b = mt * 16 + lq * 4 + r;
            const size_t o = ((size_t)b * TT + t) * HH2 + i;
            __builtin_nontemporal_store(hv_[r], rnn_out + o);
            __builtin_nontemporal_store(xn_[r], x_out + o);
        }
        const int tn = (t + 1 < TT) ? (t + 1) : t;
        #pragma unroll
        for (int r = 0; r < 4; ++r) {
            const int b = mt * 16 + lq * 4 + r;
            ipf[r] = *(const float4*)(inp + ((size_t)b * TT + tn) * 4);
        }
        phv = ph[tn]; piv = pig[tn];

        if (tid == 0) {
            const unsigned tgt = 16u * (unsigned)(t + 2);
            while (__hip_atomic_load(bcnt, __ATOMIC_RELAXED, __HIP_MEMORY_SCOPE_AGENT) < tgt) {}
        }
        __syncthreads();
    }
}

// ---------------- fc1: out[b,t] = dot(rnn_out[b,t,512:1024], fc1_w[512:1024]) + fc1_b ----------------
__global__ __launch_bounds__(256) void fc1_kernel(
    const float* __restrict__ rnn_out, const float* __restrict__ fc1_w,
    const float* __restrict__ fc1_b, float* __restrict__ out)
{
    const int wid = blockIdx.x * 4 + (threadIdx.x >> 6);  // [0, 64000)
    const int lane = threadIdx.x & 63;
    const float* p = rnn_out + (size_t)wid * HH2 + HH + lane * 8;
    const float* w = fc1_w + HH + lane * 8;
    f32x4 v0 = *(const f32x4*)(p);
    f32x4 v1 = *(const f32x4*)(p + 4);
    f32x4 w0 = *(const f32x4*)(w);
    f32x4 w1 = *(const f32x4*)(w + 4);
    float s = v0[0]*w0[0] + v0[1]*w0[1] + v0[2]*w0[2] + v0[3]*w0[3]
            + v1[0]*w1[0] + v1[1]*w1[1] + v1[2]*w1[2] + v1[3]*w1[3];
    #pragma unroll
    for (int off = 32; off; off >>= 1) s += __shfl_xor(s, off);
    if (lane == 0) out[wid] = s + fc1_b[0];
}

// ---------------- last-state extraction ----------------
__global__ __launch_bounds__(256) void last_kernel(
    const float* __restrict__ rnn_out, const float* __restrict__ x_out,
    float* __restrict__ hn_last, float* __restrict__ x_last)
{
    const int idx = blockIdx.x * 256 + threadIdx.x;  // [0, 65536)
    const int b = idx >> 10;
    const int i = idx & 1023;
    const size_t o = ((size_t)b * TT + (TT - 1)) * HH2 + i;
    hn_last[idx] = rnn_out[o];
    x_last[idx]  = x_out[o];
}

extern "C" void kernel_launch(void* const* d_in, const int* in_sizes, int n_in,
                              void* d_out, int out_size, void* d_ws, size_t ws_size,
                              hipStream_t stream) {
    const float* inp   = (const float*)d_in[0];   // [64,1000,4]
    const float* hn    = (const float*)d_in[1];   // [1,64,1024]
    const float* x     = (const float*)d_in[2];   // [1,64,1024]
    const float* inhib = (const float*)d_in[3];   // [64,1024]
    const float* ph    = (const float*)d_in[4];   // [1000]
    const float* pi    = (const float*)d_in[5];   // [1000]
    const float* s2s   = (const float*)d_in[6];   // [512,512]
    const float* a2a   = (const float*)d_in[7];
    const float* a2s   = (const float*)d_in[8];
    const float* s2a   = (const float*)d_in[9];
    const float* iw    = (const float*)d_in[10];  // [4,1024]
    const float* fw    = (const float*)d_in[11];  // [1,1024]
    const float* fb    = (const float*)d_in[12];  // [1]

    // Output tuple layout (floats): out | hn_last | rnn_out | x_last | x_out
    float* out     = (float*)d_out;               // 64000
    float* hn_last = out + 64000;                 // 65536
    float* rnn_out = out + 129536;                // 65,536,000
    float* x_last  = out + 65665536;              // 65536
    float* x_out   = out + 65731072;              // 65,536,000

    // Workspace: bar (1 KB) | pad | hbuf [2][64][1024] bf16 (256 KB)
    unsigned* bar = (unsigned*)d_ws;
    unsigned short* hbuf = (unsigned short*)((char*)d_ws + 4096);

    hipMemsetAsync(bar, 0, 1024, stream);
    rnn_persistent<<<64, 256, 0, stream>>>(inp, hn, x, inhib, ph, pi,
                                           s2s, a2a, a2s, s2a, iw,
                                           rnn_out, x_out, hbuf, bar);
    fc1_kernel<<<16000, 256, 0, stream>>>(rnn_out, fw, fb, out);
    last_kernel<<<256, 256, 0, stream>>>(rnn_out, x_out, hn_last, x_last);
}